// Round 10
// baseline (263.318 us; speedup 1.0000x reference)
//
#include <hip/hip_runtime.h>

typedef __fp16   f2  __attribute__((ext_vector_type(2)));
typedef _Float16 h4  __attribute__((ext_vector_type(4)));
typedef _Float16 v8h __attribute__((ext_vector_type(8)));
typedef float    v4f __attribute__((ext_vector_type(4)));
struct f2x2 { f2 lo, hi; };

#if __has_builtin(__builtin_amdgcn_exp2f)
#define FEXP2(x) __builtin_amdgcn_exp2f(x)   // raw v_exp_f32 (no ocml fixups)
#else
#define FEXP2(x) exp2f(x)
#endif

constexpr int Bn = 4, Nn = 2048, Dn = 1024, Hn = 16, DKn = 64, Mn = 8192;

// async global->LDS, 16B per lane; LDS dest = wave-uniform base + lane*16 (m104)
__device__ __forceinline__ void load_lds16(const _Float16* g, _Float16* l) {
    __builtin_amdgcn_global_load_lds(
        (const __attribute__((address_space(1))) void*)g,
        (__attribute__((address_space(3))) void*)l, 16, 0, 0);
}

// ---- merged cast kernel: blocks [0,8192) = X fp32->f16; [8192,12288) = W transpose+cast ----
__global__ __launch_bounds__(256) void castAll(const float* __restrict__ x,
                                               _Float16* __restrict__ y,
                                               const float* __restrict__ Wq,
                                               const float* __restrict__ Wk,
                                               const float* __restrict__ Wv,
                                               const float* __restrict__ Wo,
                                               _Float16* __restrict__ Wqkv,
                                               _Float16* __restrict__ Wto) {
    __shared__ float tile[32][33];
    const int t = threadIdx.x;
    if (blockIdx.x < 8192) {
        const int i = blockIdx.x * 256 + t;
        const float4 v = ((const float4*)x)[i];
        h4 o; o[0] = (_Float16)v.x; o[1] = (_Float16)v.y;
        o[2] = (_Float16)v.z; o[3] = (_Float16)v.w;
        ((h4*)y)[i] = o;
        return;
    }
    const int wb = blockIdx.x - 8192;
    const int which = wb >> 10, bid = wb & 1023;
    const float* W = which == 0 ? Wq : which == 1 ? Wk : which == 2 ? Wv : Wo;
    _Float16* Dst = which < 3 ? (Wqkv + ((size_t)which << 20)) : Wto;
    const int bx = bid & 31, by = bid >> 5;
    const int r = t >> 3, c4 = (t & 7) * 4;
    const float4 v = *(const float4*)&W[(size_t)(by * 32 + r) * Dn + bx * 32 + c4];
    tile[r][c4 + 0] = v.x; tile[r][c4 + 1] = v.y;
    tile[r][c4 + 2] = v.z; tile[r][c4 + 3] = v.w;
    __syncthreads();
    h4 o;
    o[0] = (_Float16)tile[c4 + 0][r];
    o[1] = (_Float16)tile[c4 + 1][r];
    o[2] = (_Float16)tile[c4 + 2][r];
    o[3] = (_Float16)tile[c4 + 3][r];
    *(h4*)&Dst[(size_t)(bx * 32 + r) * Dn + by * 32 + c4] = o;
}

// ======================================================================
// GEMMs R10: TLP instead of deeper ILP. R9 decisive reading: XCD swizzle
// cut FETCH 78.9->59.5MB but dur flat; Occupancy 14.4% exposed the real
// stall -- 128KB LDS = 1 block/CU, so every vmcnt/barrier drain idles the
// whole CU (MfmaUtil 27 + VALUBusy 12 = 39% issue, 60% idle).
// Change: regions 4 -> 2 (plain K-step double-buffer, stage-1-ahead,
// vmcnt(0) per K-step). QKV LDS 128 -> 64KB, gemmo 96 -> 48KB -> 2
// blocks/CU; the co-resident block's waves cover the drain stalls (m97's
// mechanism). Bonus: 384 QKV blocks all co-resident (no round quantization).
// Hazard ledger: stage slot p+1 (region (p+1)&1) issues in step p, after
// the end barrier of step p-1 whose reads last touched that region (WAR);
// vmcnt(0)+barrier at end of step p publishes slot p+1 (RAW). All 32 slots
// staged once: prologue slot 0, steps 0..30 stage 1..31.
// Addressing/swizzle byte-identical to R6-R9 (0 conflicts measured):
// region = 8192 f16, rows 32 f16, chunk swizzle (t&3)^((t>>3)&3) on the
// global source, read swz = quad^((l16>>1)&3), XCD-bijective block map.
// ======================================================================
#define MFMA16(A, B, C) __builtin_amdgcn_mfma_f32_16x16x32_f16((A), (B), (C), 0, 0, 0)

// ---------- fused QKV GEMM: [8192,1024] @ [3072,1024]^T ----------
// 256x256 tile, per-wave 128x64 (2M x 4N). grid 32*12 = 384 blocks.
__global__ __launch_bounds__(512, 2) void gemmqkv(const _Float16* __restrict__ A,
                                                  const _Float16* __restrict__ Wt,
                                                  _Float16* __restrict__ Qo,
                                                  _Float16* __restrict__ Ko,
                                                  _Float16* __restrict__ Vo)
{
    __shared__ __align__(16) _Float16 As[2 * 8192];
    __shared__ __align__(16) _Float16 Bs[2 * 8192];
    // XCD swizzle: 384 % 8 == 0 -> bijective chunked map (48 tiles/XCD)
    const int wgid = (blockIdx.x & 7) * 48 + (blockIdx.x >> 3);
    const int bx = wgid % 12, by = wgid / 12;
    const int m0 = by * 256, n0 = bx * 256;
    const _Float16* Abase = A + (size_t)m0 * Dn;
    const _Float16* Bbase = Wt + (size_t)n0 * Dn;

    const int t = threadIdx.x, lane = t & 63, w = t >> 6;
    const int quad = lane >> 4, l16 = lane & 15;
    const int wm = w >> 2, wn = w & 3;
    const int rA = t >> 2;
    const int gc = ((t & 3) ^ ((t >> 3) & 3)) * 8;   // source-side XOR swizzle
    const _Float16* pA0 = Abase + (size_t)rA * Dn + gc;
    const _Float16* pA1 = pA0 + (size_t)128 * Dn;    // A rows 128..255
    const _Float16* pB0 = Bbase + (size_t)rA * Dn + gc;
    const _Float16* pB1 = pB0 + (size_t)128 * Dn;    // B rows 128..255
    auto stageA = [&](int s) {                       // slot s = 32-wide K-step
        const int reg = s & 1, ko = s * 32;
        load_lds16(pA0 + ko, As + reg * 8192 + w * 512);
        load_lds16(pA1 + ko, As + reg * 8192 + 4096 + w * 512);
    };
    auto stageB = [&](int s) {
        const int reg = s & 1, ko = s * 32;
        load_lds16(pB0 + ko, Bs + reg * 8192 + w * 512);
        load_lds16(pB1 + ko, Bs + reg * 8192 + 4096 + w * 512);
    };
    const int swz  = (quad ^ ((l16 >> 1) & 3)) * 8;
    const int aoff = (wm * 128 + l16) * 32 + swz;
    const int boff = (wn * 64 + l16) * 32 + swz;

    v4f acc[8][4];
#pragma unroll
    for (int i = 0; i < 8; ++i)
#pragma unroll
        for (int j = 0; j < 4; ++j) acc[i][j] = v4f{0.f, 0.f, 0.f, 0.f};

    stageA(0); stageB(0);                            // prologue: slot 0
    asm volatile("s_waitcnt vmcnt(0)" ::: "memory");
    __builtin_amdgcn_s_barrier();

#define QKV_KSTEP(REG, S, DOST) do {                                             \
    const _Float16* Ab_ = As + (REG) * 8192 + aoff;                              \
    const _Float16* Bb_ = Bs + (REG) * 8192 + boff;                              \
    v8h aL[4], aH[4], bL[4];                                                     \
    _Pragma("unroll") for (int q2 = 0; q2 < 4; ++q2) {                           \
        aL[q2] = *(const v8h*)(Ab_ + q2 * 512);                                  \
        bL[q2] = *(const v8h*)(Bb_ + q2 * 512);                                  \
    }                                                                            \
    if (DOST) stageA(S);                                                         \
    __builtin_amdgcn_s_barrier();                                                \
    asm volatile("s_waitcnt lgkmcnt(0)" ::: "memory");                           \
    __builtin_amdgcn_s_setprio(1);                                               \
    _Pragma("unroll") for (int i2 = 0; i2 < 4; ++i2)                             \
        _Pragma("unroll") for (int j2 = 0; j2 < 4; ++j2)                         \
            acc[i2][j2] = MFMA16(aL[i2], bL[j2], acc[i2][j2]);                   \
    __builtin_amdgcn_s_setprio(0);                                               \
    __builtin_amdgcn_s_barrier();                                                \
    _Pragma("unroll") for (int q2 = 0; q2 < 4; ++q2)                             \
        aH[q2] = *(const v8h*)(Ab_ + 2048 + q2 * 512);                           \
    if (DOST) stageB(S);                                                         \
    __builtin_amdgcn_s_barrier();                                                \
    asm volatile("s_waitcnt lgkmcnt(0)" ::: "memory");                           \
    __builtin_amdgcn_s_setprio(1);                                               \
    _Pragma("unroll") for (int i2 = 0; i2 < 4; ++i2)                             \
        _Pragma("unroll") for (int j2 = 0; j2 < 4; ++j2)                         \
            acc[4 + i2][j2] = MFMA16(aH[i2], bL[j2], acc[4 + i2][j2]);           \
    __builtin_amdgcn_s_setprio(0);                                               \
    if (DOST) asm volatile("s_waitcnt vmcnt(0)" ::: "memory");                   \
    __builtin_amdgcn_s_barrier();                                                \
} while (0)

    // 32 K-steps; step p uses region p&1, stages slot p+1 (steps 0..30)
    for (int p2 = 0; p2 < 15; ++p2) {
        QKV_KSTEP(0, 2 * p2 + 1, true);
        QKV_KSTEP(1, 2 * p2 + 2, true);
    }
    QKV_KSTEP(0, 31, true);      // p=30: stages last slot 31
    QKV_KSTEP(1, 0, false);      // p=31: no stage, no vm wait
#undef QKV_KSTEP

    const int sec = n0 >> 10;                      // block-uniform: 0=Q 1=K 2=V
    if (sec < 2) {
        _Float16* C = sec ? Ko : Qo;
        // Q pre-scaled by 1/sqrt(DK) * log2(e) so flash uses exp2 directly
        const float scale = sec ? 1.0f : 0.125f * 1.44269504f;
#pragma unroll
        for (int mf = 0; mf < 8; ++mf) {
            const int mbase = m0 + wm * 128 + mf * 16 + quad * 4;
#pragma unroll
            for (int nf = 0; nf < 4; ++nf) {
                const int nl = (n0 + wn * 64 + nf * 16 + l16) & 1023;
                const int h = nl >> 6, dk = nl & 63;
#pragma unroll
                for (int r = 0; r < 4; ++r) {
                    const int m = mbase + r, b = m >> 11, nr = m & (Nn - 1);
                    C[((size_t)(b * Hn + h) * Nn + nr) * DKn + dk] = (_Float16)(acc[mf][nf][r] * scale);
                }
            }
        }
    } else {
#pragma unroll
        for (int mf = 0; mf < 8; ++mf) {
            const int mbase = m0 + wm * 128 + mf * 16 + quad * 4;
            const int b = mbase >> 11, nr = mbase & (Nn - 1);
#pragma unroll
            for (int nf = 0; nf < 4; ++nf) {
                const int nl = (n0 + wn * 64 + nf * 16 + l16) & 1023;
                const int h = nl >> 6, dk = nl & 63;
                h4 o; o[0] = (_Float16)acc[mf][nf][0]; o[1] = (_Float16)acc[mf][nf][1];
                o[2] = (_Float16)acc[mf][nf][2]; o[3] = (_Float16)acc[mf][nf][3];
                *(h4*)&Vo[((size_t)(b * Hn + h) * DKn + dk) * Nn + nr] = o;
            }
        }
    }
}

// ---------- output GEMM: [8192,1024] @ [1024,1024]^T -> fp32 row-major ----------
// 256x128 tile (grid 256), per-wave 64x64. LDS 48KB -> 2+ blocks/CU.
__global__ __launch_bounds__(512, 2) void gemmo(const _Float16* __restrict__ A,
                                                const _Float16* __restrict__ Wt,
                                                float* __restrict__ C)
{
    __shared__ __align__(16) _Float16 As[2 * 8192];
    __shared__ __align__(16) _Float16 Bs[2 * 4096];
    // XCD swizzle: 256 % 8 == 0 -> 32 tiles/XCD, contiguous (by,bx) range
    const int wgid = (blockIdx.x & 7) * 32 + (blockIdx.x >> 3);
    const int bx = wgid & 7, by = wgid >> 3;
    const int m0 = by * 256, n0 = bx * 128;
    const _Float16* Abase = A + (size_t)m0 * Dn;
    const _Float16* Bbase = Wt + (size_t)n0 * Dn;

    const int t = threadIdx.x, lane = t & 63, w = t >> 6;
    const int quad = lane >> 4, l16 = lane & 15;
    const int wm = w & 3, wn = w >> 2;
    const int rA = t >> 2;
    const int gc = ((t & 3) ^ ((t >> 3) & 3)) * 8;
    const _Float16* pA0 = Abase + (size_t)rA * Dn + gc;
    const _Float16* pA1 = pA0 + (size_t)128 * Dn;
    const _Float16* pB0 = Bbase + (size_t)rA * Dn + gc;
    auto stage3 = [&](int s) {
        const int reg = s & 1, ko = s * 32;
        load_lds16(pA0 + ko, As + reg * 8192 + w * 512);
        load_lds16(pA1 + ko, As + reg * 8192 + 4096 + w * 512);
        load_lds16(pB0 + ko, Bs + reg * 4096 + w * 512);
    };
    const int swz  = (quad ^ ((l16 >> 1) & 3)) * 8;
    const int aoff = (wm * 64 + l16) * 32 + swz;
    const int boff = (wn * 64 + l16) * 32 + swz;

    v4f acc[4][4];
#pragma unroll
    for (int i = 0; i < 4; ++i)
#pragma unroll
        for (int j = 0; j < 4; ++j) acc[i][j] = v4f{0.f, 0.f, 0.f, 0.f};

    stage3(0);                                   // prologue: slot 0
    asm volatile("s_waitcnt vmcnt(0)" ::: "memory");
    __builtin_amdgcn_s_barrier();

#define O_KSTEP(REG, S, DOST) do {                                               \
    const _Float16* Ab_ = As + (REG) * 8192 + aoff;                              \
    const _Float16* Bb_ = Bs + (REG) * 4096 + boff;                              \
    v8h aL[4], bL[4];                                                            \
    _Pragma("unroll") for (int q2 = 0; q2 < 4; ++q2) {                           \
        aL[q2] = *(const v8h*)(Ab_ + q2 * 512);                                  \
        bL[q2] = *(const v8h*)(Bb_ + q2 * 512);                                  \
    }                                                                            \
    if (DOST) stage3(S);                                                         \
    __builtin_amdgcn_s_barrier();                                                \
    asm volatile("s_waitcnt lgkmcnt(0)" ::: "memory");                           \
    __builtin_amdgcn_s_setprio(1);                                               \
    _Pragma("unroll") for (int i2 = 0; i2 < 4; ++i2)                             \
        _Pragma("unroll") for (int j2 = 0; j2 < 4; ++j2)                         \
            acc[i2][j2] = MFMA16(aL[i2], bL[j2], acc[i2][j2]);                   \
    __builtin_amdgcn_s_setprio(0);                                               \
    if (DOST) asm volatile("s_waitcnt vmcnt(0)" ::: "memory");                   \
    __builtin_amdgcn_s_barrier();                                                \
} while (0)

    for (int p2 = 0; p2 < 15; ++p2) {
        O_KSTEP(0, 2 * p2 + 1, true);
        O_KSTEP(1, 2 * p2 + 2, true);
    }
    O_KSTEP(0, 31, true);       // p=30: stages last slot 31
    O_KSTEP(1, 0, false);       // p=31
#undef O_KSTEP

#pragma unroll
    for (int mf = 0; mf < 4; ++mf) {
        const int mbase = m0 + wm * 64 + mf * 16 + quad * 4;
#pragma unroll
        for (int nf = 0; nf < 4; ++nf) {
            const int n = n0 + wn * 64 + nf * 16 + l16;
#pragma unroll
            for (int r = 0; r < 4; ++r)
                C[(size_t)(mbase + r) * Dn + n] = acc[mf][nf][r];
        }
    }
}

// ---------------- flash v5 (R6/R9 version, single-buffer) ----------------
// R7's K/V double-buffer REGRESSED (-6us): 48KB LDS cut occupancy 5->3
// blocks/CU while K/V (512KB/head) is L2-resident across the 16 q-tile
// blocks per bh -> staging latency was already TLP-hidden (Common-mistake
// #7). Blocks sharing bh are 64 apart -> same XCD (64 % 8 == 0).
__global__ __launch_bounds__(256) void flashv5(const _Float16* __restrict__ Q,
                                               const _Float16* __restrict__ K,
                                               const _Float16* __restrict__ Vt,
                                               _Float16* __restrict__ O)
{
    __shared__ __align__(16) _Float16 KS[64 * 64];     // [key][dk], chunk-swizzled
    __shared__ __align__(16) _Float16 VS[64 * 64];     // [dk][key], chunk-swizzled
    __shared__ __align__(16) _Float16 Ps[4][32 * 64];  // per-wave P, chunk-swizzled

    const int t = threadIdx.x;
    const int lane = t & 63, w = t >> 6;
    const int quad = lane >> 4, l16 = lane & 15;
    const int bh = blockIdx.x & 63;                    // fast-varying (L2 locality)
    const int qtile = 15 - (blockIdx.x >> 6);          // heaviest first
    const int b = bh >> 4, h = bh & 15;
    const int qb = qtile * 128 + w * 32;

    const _Float16* Qg = Q  + (size_t)bh * Nn * DKn;
    const _Float16* Kg = K  + (size_t)bh * Nn * DKn;
    const _Float16* Vg = Vt + (size_t)bh * DKn * Nn;

    auto stage = [&](int kt) {
        const int k0 = kt * 64;
#pragma unroll
        for (int jj = 0; jj < 2; ++jj) {
            const int ci = jj * 256 + w * 64 + lane;   // slot (r*8 + c)
            const int r = ci >> 3, c = ci & 7;
            const int gc = (c ^ (r & 7)) * 8;          // XOR chunk swizzle
            load_lds16(Kg + (size_t)(k0 + r) * DKn + gc, &KS[(jj * 256 + w * 64) * 8]);
            load_lds16(Vg + (size_t)r * Nn + k0 + gc,    &VS[(jj * 256 + w * 64) * 8]);
        }
    };
#define SWZ(arr, r, c) (*(const v8h*)&(arr)[(r) * 64 + (((c) ^ ((r) & 7)) * 8)])

    v8h qf[2][2];
#pragma unroll
    for (int qq = 0; qq < 2; ++qq)
#pragma unroll
        for (int ks = 0; ks < 2; ++ks)
            qf[qq][ks] = *(const v8h*)&Qg[(size_t)(qb + qq * 16 + l16) * DKn + ks * 32 + quad * 8];

    v8h ones;
#pragma unroll
    for (int i = 0; i < 8; ++i) ones[i] = (_Float16)1.0f;

    v4f o[2][4];
#pragma unroll
    for (int mq = 0; mq < 2; ++mq)
#pragma unroll
        for (int nt = 0; nt < 4; ++nt) o[mq][nt] = v4f{0.f, 0.f, 0.f, 0.f};
    v4f ol[2] = {v4f{0.f, 0.f, 0.f, 0.f}, v4f{0.f, 0.f, 0.f, 0.f}};

    const int NKT  = 2 * qtile + 2;                    // block-uniform
    const int diag = 2 * qtile + (w >> 1);             // wave's masked tile

    for (int kt = 0; kt < NKT; ++kt) {
        stage(kt);
        __syncthreads();                               // drains vmcnt (staging done)
        if (kt <= diag) {
            const int k0 = kt * 64;
            auto ptile = [&](bool domask) {
#pragma unroll
                for (int kk = 0; kk < 4; ++kk) {
                    v4f s0 = v4f{0.f, 0.f, 0.f, 0.f}, s1 = v4f{0.f, 0.f, 0.f, 0.f};
#pragma unroll
                    for (int ks = 0; ks < 2; ++ks) {
                        const v8h ak = SWZ(KS, kk * 16 + l16, ks * 4 + quad);
                        s0 = __builtin_amdgcn_mfma_f32_16x16x32_f16(ak, qf[0][ks], s0, 0, 0, 0);
                        s1 = __builtin_amdgcn_mfma_f32_16x16x32_f16(ak, qf[1][ks], s1, 0, 0, 0);
                    }
                    const int key0 = k0 + kk * 16 + quad * 4;
#pragma unroll
                    for (int qq = 0; qq < 2; ++qq) {
                        const v4f sv = qq ? s1 : s0;
                        const int q = qb + qq * 16 + l16;
                        float p[4];
#pragma unroll
                        for (int r = 0; r < 4; ++r) {
                            float x = sv[r];
                            if (domask) x = (key0 + r > q) ? -1e9f : x;
                            p[r] = FEXP2(x);           // Q pre-scaled by log2e/8
                        }
                        f2x2 pkr;
                        pkr.lo = __builtin_amdgcn_cvt_pkrtz(p[0], p[1]);
                        pkr.hi = __builtin_amdgcn_cvt_pkrtz(p[2], p[3]);
                        const h4 pk = __builtin_bit_cast(h4, pkr);
                        const int prow = qq * 16 + l16;
                        const int pch  = kk * 2 + (quad >> 1);
                        *(h4*)&Ps[w][prow * 64 + ((pch ^ (prow & 7)) * 8 + (quad & 1) * 4)] = pk;
                    }
                }
#pragma unroll
                for (int ks = 0; ks < 2; ++ks)
#pragma unroll
                    for (int mq = 0; mq < 2; ++mq) {
                        const int arow = mq * 16 + l16;
                        const int ach  = ks * 4 + quad;
                        const v8h a = *(const v8h*)&Ps[w][arow * 64 + ((ach ^ (arow & 7)) * 8)];
#pragma unroll
                        for (int nt = 0; nt < 4; ++nt) {
                            const v8h bvv = SWZ(VS, nt * 16 + l16, ks * 4 + quad);
                            o[mq][nt] = __builtin_amdgcn_mfma_f32_16x16x32_f16(a, bvv, o[mq][nt], 0, 0, 0);
                        }
                        ol[mq] = __builtin_amdgcn_mfma_f32_16x16x32_f16(a, ones, ol[mq], 0, 0, 0);
                    }
            };
            if (kt == diag) ptile(true); else ptile(false);
        }
        __syncthreads();                               // all reads done before next stage
    }
#undef SWZ

    _Float16* Op = O + (size_t)b * Nn * Dn + h * DKn;
#pragma unroll
    for (int mq = 0; mq < 2; ++mq)
#pragma unroll
        for (int r = 0; r < 4; ++r) {
            const float li = 1.0f / ol[mq][r];
            const int qrow = qb + mq * 16 + quad * 4 + r;
#pragma unroll
            for (int nt = 0; nt < 4; ++nt)
                Op[(size_t)qrow * Dn + nt * 16 + l16] = (_Float16)(o[mq][nt][r] * li);
        }
}

extern "C" void kernel_launch(void* const* d_in, const int* in_sizes, int n_in,
                              void* d_out, int out_size, void* d_ws, size_t ws_size,
                              hipStream_t stream)
{
    const float* X  = (const float*)d_in[0];
    // d_in[1] = additive causal mask; regenerated inline in flashv5.
    const float* Wq = (const float*)d_in[2];
    const float* Wk = (const float*)d_in[3];
    const float* Wv = (const float*)d_in[4];
    const float* Wo = (const float*)d_in[5];

    char* ws = (char*)d_ws;
    _Float16* Xh   = (_Float16*)ws;                      // 16 MB
    _Float16* Wqkv = (_Float16*)(ws + (16u << 20));      // 6 MB  [3072][1024]
    _Float16* Wto  = Wqkv + (3u << 20);                  // 2 MB
    _Float16* Qh   = Wto + (1u << 20);                   // 16 MB each
    _Float16* Kh   = Qh + (size_t)Mn * Dn;
    _Float16* Vth  = Kh + (size_t)Mn * Dn;
    _Float16* Ah   = Vth + (size_t)Mn * Dn;              // total 88 MB

    castAll<<<12288, 256, 0, stream>>>(X, Xh, Wq, Wk, Wv, Wo, Wqkv, Wto);
    gemmqkv<<<384, 512, 0, stream>>>(Xh, Wqkv, Qh, Kh, Vth);
    flashv5<<<1024, 256, 0, stream>>>(Qh, Kh, Vth, Ah);
    gemmo<<<256, 512, 0, stream>>>(Ah, Wto, (float*)d_out);
}

// Round 11
// 249.683 us; speedup vs baseline: 1.0546x; 1.0546x over previous
//
#include <hip/hip_runtime.h>

typedef __fp16   f2  __attribute__((ext_vector_type(2)));
typedef _Float16 h4  __attribute__((ext_vector_type(4)));
typedef _Float16 v8h __attribute__((ext_vector_type(8)));
typedef float    v4f __attribute__((ext_vector_type(4)));
struct f2x2 { f2 lo, hi; };

#if __has_builtin(__builtin_amdgcn_exp2f)
#define FEXP2(x) __builtin_amdgcn_exp2f(x)   // raw v_exp_f32 (no ocml fixups)
#else
#define FEXP2(x) exp2f(x)
#endif

constexpr int Bn = 4, Nn = 2048, Dn = 1024, Hn = 16, DKn = 64, Mn = 8192;

// async global->LDS, 16B per lane; LDS dest = wave-uniform base + lane*16 (m104)
__device__ __forceinline__ void load_lds16(const _Float16* g, _Float16* l) {
    __builtin_amdgcn_global_load_lds(
        (const __attribute__((address_space(1))) void*)g,
        (__attribute__((address_space(3))) void*)l, 16, 0, 0);
}

// ---- merged cast kernel: blocks [0,8192) = X fp32->f16; [8192,12288) = W transpose+cast ----
__global__ __launch_bounds__(256) void castAll(const float* __restrict__ x,
                                               _Float16* __restrict__ y,
                                               const float* __restrict__ Wq,
                                               const float* __restrict__ Wk,
                                               const float* __restrict__ Wv,
                                               const float* __restrict__ Wo,
                                               _Float16* __restrict__ Wqkv,
                                               _Float16* __restrict__ Wto) {
    __shared__ float tile[32][33];
    const int t = threadIdx.x;
    if (blockIdx.x < 8192) {
        const int i = blockIdx.x * 256 + t;
        const float4 v = ((const float4*)x)[i];
        h4 o; o[0] = (_Float16)v.x; o[1] = (_Float16)v.y;
        o[2] = (_Float16)v.z; o[3] = (_Float16)v.w;
        ((h4*)y)[i] = o;
        return;
    }
    const int wb = blockIdx.x - 8192;
    const int which = wb >> 10, bid = wb & 1023;
    const float* W = which == 0 ? Wq : which == 1 ? Wk : which == 2 ? Wv : Wo;
    _Float16* Dst = which < 3 ? (Wqkv + ((size_t)which << 20)) : Wto;
    const int bx = bid & 31, by = bid >> 5;
    const int r = t >> 3, c4 = (t & 7) * 4;
    const float4 v = *(const float4*)&W[(size_t)(by * 32 + r) * Dn + bx * 32 + c4];
    tile[r][c4 + 0] = v.x; tile[r][c4 + 1] = v.y;
    tile[r][c4 + 2] = v.z; tile[r][c4 + 3] = v.w;
    __syncthreads();
    h4 o;
    o[0] = (_Float16)tile[c4 + 0][r];
    o[1] = (_Float16)tile[c4 + 1][r];
    o[2] = (_Float16)tile[c4 + 2][r];
    o[3] = (_Float16)tile[c4 + 3][r];
    *(h4*)&Dst[(size_t)(bx * 32 + r) * Dn + by * 32 + c4] = o;
}

// ======================================================================
// GEMMs R11: R9 schedule (best measured) + exact-round QKV grid.
// R10's 2-region TLP attempt REGRESSED (80.9 vs 75.7): per-K-step vmcnt(0)
// cost more in-block than co-residency returned -> reverted to R9's
// 4-region stage-3-ahead counted-vmcnt structure (hazard ledger in R3/R6).
// R11 change: QKV tile 256x256 -> 256x192, grid 384 -> 512 = EXACTLY 2
// rounds of 256 CUs. R9's makespan was 2 x block-time with round 2 only
// half-full (384 = 256 + 128); same 2-round makespan now covers 33% more
// tiles. Per-wave 128x48 (acc[8][3]); per-K-step model: MFMA 931 + LDS
// reads 1056 + staging ~2400 cyc vs 2839 -> ~64us projected.
// B staging: 192 rows = pass1 (all waves, rows 0..127) + pass2 (t<256,
// rows 128..191; max source row 3071, no OOB). Per-wave loads/slot = 3 or
// 4 -> uniform CONSERVATIVE vmcnt(6) (= 2 full slots for 3-load waves,
// >=1.5 slots for 4-load waves; correct whether or not the compiler
// branches around the masked pass-2 load). Taper 6 -> 3 -> 0 re-derived.
// Read-swizzle identity intact: 48 and 16 == 0 mod 8 so row==l16 mod 8.
// Epilogue: 192 does not divide 1024 -> section (Q/K/V) resolved per nf
// (base = n0+wn*48+nf*16 is a multiple of 16 -> a 16-lane group never
// spans a 1024 boundary).
// ======================================================================
#define MFMA16(A, B, C) __builtin_amdgcn_mfma_f32_16x16x32_f16((A), (B), (C), 0, 0, 0)

// ---------- fused QKV GEMM: [8192,1024] @ [3072,1024]^T ----------
// 256x192 tile, per-wave 128x48 (2M x 4N). grid 32*16 = 512 blocks.
__global__ __launch_bounds__(512, 2) void gemmqkv(const _Float16* __restrict__ A,
                                                  const _Float16* __restrict__ Wt,
                                                  _Float16* __restrict__ Qo,
                                                  _Float16* __restrict__ Ko,
                                                  _Float16* __restrict__ Vo)
{
    __shared__ __align__(16) _Float16 As[4 * 8192];
    __shared__ __align__(16) _Float16 Bs[4 * 6144];
    // XCD swizzle: 512 % 8 == 0 -> bijective chunked map (64 tiles/XCD,
    // = 4 contiguous A-panels per XCD)
    const int wgid = (blockIdx.x & 7) * 64 + (blockIdx.x >> 3);
    const int bx = wgid & 15, by = wgid >> 4;
    const int m0 = by * 256, n0 = bx * 192;
    const _Float16* Abase = A + (size_t)m0 * Dn;
    const _Float16* Bbase = Wt + (size_t)n0 * Dn;

    const int t = threadIdx.x, lane = t & 63, w = t >> 6;
    const int quad = lane >> 4, l16 = lane & 15;
    const int wm = w >> 2, wn = w & 3;
    const int rA = t >> 2;
    const int gc = ((t & 3) ^ ((t >> 3) & 3)) * 8;   // source-side XOR swizzle
    const _Float16* pA0 = Abase + (size_t)rA * Dn + gc;
    const _Float16* pA1 = pA0 + (size_t)128 * Dn;    // A rows 128..255
    const _Float16* pB0 = Bbase + (size_t)rA * Dn + gc;
    const _Float16* pB1 = pB0 + (size_t)128 * Dn;    // B rows 128..191 (t<256)
    auto stageA = [&](int ts, int sh) {
        const int reg = (ts & 1) * 2 + sh, ko = ts * 64 + sh * 32;
        load_lds16(pA0 + ko, As + reg * 8192 + w * 512);
        load_lds16(pA1 + ko, As + reg * 8192 + 4096 + w * 512);
    };
    auto stageB = [&](int ts, int sh) {
        const int reg = (ts & 1) * 2 + sh, ko = ts * 64 + sh * 32;
        load_lds16(pB0 + ko, Bs + reg * 6144 + w * 512);
        if (t < 256)                                  // rows 128..191 only
            load_lds16(pB1 + ko, Bs + reg * 6144 + 4096 + w * 512);
    };
    const int swz  = (quad ^ ((l16 >> 1) & 3)) * 8;
    const int aoff = (wm * 128 + l16) * 32 + swz;
    const int boff = (wn * 48 + l16) * 32 + swz;

    v4f acc[8][3];
#pragma unroll
    for (int i = 0; i < 8; ++i)
#pragma unroll
        for (int j = 0; j < 3; ++j) acc[i][j] = v4f{0.f, 0.f, 0.f, 0.f};

    // prologue: slots 0,1,2 (A,B pairs in order); vmcnt(6) -> slot 0 done
    stageA(0, 0); stageB(0, 0); stageA(0, 1); stageB(0, 1); stageA(1, 0); stageB(1, 0);
    asm volatile("s_waitcnt vmcnt(6)" ::: "memory");
    __builtin_amdgcn_s_barrier();

#define QKV_KSTEP(REG, TS, SH, DOST, VM, DOVM) do {                              \
    const _Float16* Ab_ = As + (REG) * 8192 + aoff;                              \
    const _Float16* Bb_ = Bs + (REG) * 6144 + boff;                              \
    v8h aL[4], aH[4], bL[3];                                                     \
    _Pragma("unroll") for (int q2 = 0; q2 < 4; ++q2)                             \
        aL[q2] = *(const v8h*)(Ab_ + q2 * 512);                                  \
    _Pragma("unroll") for (int q2 = 0; q2 < 3; ++q2)                             \
        bL[q2] = *(const v8h*)(Bb_ + q2 * 512);                                  \
    if (DOST) stageA((TS), (SH));                                                \
    __builtin_amdgcn_s_barrier();                                                \
    asm volatile("s_waitcnt lgkmcnt(0)" ::: "memory");                           \
    __builtin_amdgcn_s_setprio(1);                                               \
    _Pragma("unroll") for (int i2 = 0; i2 < 4; ++i2)                             \
        _Pragma("unroll") for (int j2 = 0; j2 < 3; ++j2)                         \
            acc[i2][j2] = MFMA16(aL[i2], bL[j2], acc[i2][j2]);                   \
    __builtin_amdgcn_s_setprio(0);                                               \
    __builtin_amdgcn_s_barrier();                                                \
    _Pragma("unroll") for (int q2 = 0; q2 < 4; ++q2)                             \
        aH[q2] = *(const v8h*)(Ab_ + 2048 + q2 * 512);                           \
    if (DOST) stageB((TS), (SH));                                                \
    __builtin_amdgcn_s_barrier();                                                \
    asm volatile("s_waitcnt lgkmcnt(0)" ::: "memory");                           \
    __builtin_amdgcn_s_setprio(1);                                               \
    _Pragma("unroll") for (int i2 = 0; i2 < 4; ++i2)                             \
        _Pragma("unroll") for (int j2 = 0; j2 < 3; ++j2)                         \
            acc[4 + i2][j2] = MFMA16(aH[i2], bL[j2], acc[4 + i2][j2]);           \
    __builtin_amdgcn_s_setprio(0);                                               \
    if (DOVM) asm volatile("s_waitcnt " VM ::: "memory");                        \
    __builtin_amdgcn_s_barrier();                                                \
} while (0)

    // 32 K-steps; main loop p=0..27, peel 28..31 with tapered waits
    for (int tt = 0; tt < 14; tt += 2) {
        QKV_KSTEP(0, tt + 1, 1, true, "vmcnt(6)", true);
        QKV_KSTEP(1, tt + 2, 0, true, "vmcnt(6)", true);
        QKV_KSTEP(2, tt + 2, 1, true, "vmcnt(6)", true);
        QKV_KSTEP(3, tt + 3, 0, true, "vmcnt(6)", true);
    }
    QKV_KSTEP(0, 15, 1, true,  "vmcnt(6)", true);   // p=28: stages last slot 31
    QKV_KSTEP(1, 0, 0, false, "vmcnt(3)", true);    // p=29
    QKV_KSTEP(2, 0, 0, false, "vmcnt(0)", true);    // p=30
    QKV_KSTEP(3, 0, 0, false, "vmcnt(0)", false);   // p=31 (no wait)
#undef QKV_KSTEP

    // Epilogue: section resolved per column group (192 spans Q/K/V bounds).
#pragma unroll
    for (int mf = 0; mf < 8; ++mf) {
        const int mbase = m0 + wm * 128 + mf * 16 + quad * 4;
        const int b = mbase >> 11, nr = mbase & (Nn - 1);  // +r never crosses
#pragma unroll
        for (int nf = 0; nf < 3; ++nf) {
            const int nG = n0 + wn * 48 + nf * 16 + l16;   // [0, 3072)
            const int sec = nG >> 10, nl = nG & 1023;
            const int h = nl >> 6, dk = nl & 63;
            if (sec < 2) {
                _Float16* C = sec ? Ko : Qo;
                // Q pre-scaled by 1/sqrt(DK) * log2(e) so flash uses exp2
                const float scale = sec ? 1.0f : 0.125f * 1.44269504f;
#pragma unroll
                for (int r = 0; r < 4; ++r)
                    C[((size_t)(b * Hn + h) * Nn + (nr + r)) * DKn + dk] =
                        (_Float16)(acc[mf][nf][r] * scale);
            } else {
                h4 o; o[0] = (_Float16)acc[mf][nf][0]; o[1] = (_Float16)acc[mf][nf][1];
                o[2] = (_Float16)acc[mf][nf][2]; o[3] = (_Float16)acc[mf][nf][3];
                *(h4*)&Vo[((size_t)(b * Hn + h) * DKn + dk) * Nn + nr] = o;
            }
        }
    }
}

// ---------- output GEMM: [8192,1024] @ [1024,1024]^T -> fp32 row-major ----------
// 256x128 tile (grid 256 = exactly 1 full round of 256 CUs), per-wave 64x64.
// R9 version (4-region, counted vmcnt).
__global__ __launch_bounds__(512, 2) void gemmo(const _Float16* __restrict__ A,
                                                const _Float16* __restrict__ Wt,
                                                float* __restrict__ C)
{
    __shared__ __align__(16) _Float16 As[4 * 8192];
    __shared__ __align__(16) _Float16 Bs[4 * 4096];
    // XCD swizzle: 256 % 8 == 0 -> 32 tiles/XCD, contiguous (by,bx) range
    const int wgid = (blockIdx.x & 7) * 32 + (blockIdx.x >> 3);
    const int bx = wgid & 7, by = wgid >> 3;
    const int m0 = by * 256, n0 = bx * 128;
    const _Float16* Abase = A + (size_t)m0 * Dn;
    const _Float16* Bbase = Wt + (size_t)n0 * Dn;

    const int t = threadIdx.x, lane = t & 63, w = t >> 6;
    const int quad = lane >> 4, l16 = lane & 15;
    const int wm = w & 3, wn = w >> 2;
    const int rA = t >> 2;
    const int gc = ((t & 3) ^ ((t >> 3) & 3)) * 8;
    const _Float16* pA0 = Abase + (size_t)rA * Dn + gc;
    const _Float16* pA1 = pA0 + (size_t)128 * Dn;
    const _Float16* pB0 = Bbase + (size_t)rA * Dn + gc;
    auto stage3 = [&](int ts, int sh) {
        const int reg = (ts & 1) * 2 + sh, ko = ts * 64 + sh * 32;
        load_lds16(pA0 + ko, As + reg * 8192 + w * 512);
        load_lds16(pA1 + ko, As + reg * 8192 + 4096 + w * 512);
        load_lds16(pB0 + ko, Bs + reg * 4096 + w * 512);
    };
    const int swz  = (quad ^ ((l16 >> 1) & 3)) * 8;
    const int aoff = (wm * 64 + l16) * 32 + swz;
    const int boff = (wn * 64 + l16) * 32 + swz;

    v4f acc[4][4];
#pragma unroll
    for (int i = 0; i < 4; ++i)
#pragma unroll
        for (int j = 0; j < 4; ++j) acc[i][j] = v4f{0.f, 0.f, 0.f, 0.f};

    stage3(0, 0); stage3(0, 1); stage3(1, 0);    // prologue: slots 0,1,2
    asm volatile("s_waitcnt vmcnt(6)" ::: "memory");
    __builtin_amdgcn_s_barrier();

#define O_KSTEP(REG, TS, SH, DOST, VM, DOVM) do {                                \
    const _Float16* Ab_ = As + (REG) * 8192 + aoff;                              \
    const _Float16* Bb_ = Bs + (REG) * 4096 + boff;                              \
    v8h aL[4], bL[4];                                                            \
    _Pragma("unroll") for (int q2 = 0; q2 < 4; ++q2) {                           \
        aL[q2] = *(const v8h*)(Ab_ + q2 * 512);                                  \
        bL[q2] = *(const v8h*)(Bb_ + q2 * 512);                                  \
    }                                                                            \
    if (DOST) stage3((TS), (SH));                                                \
    __builtin_amdgcn_s_barrier();                                                \
    asm volatile("s_waitcnt lgkmcnt(0)" ::: "memory");                           \
    __builtin_amdgcn_s_setprio(1);                                               \
    _Pragma("unroll") for (int i2 = 0; i2 < 4; ++i2)                             \
        _Pragma("unroll") for (int j2 = 0; j2 < 4; ++j2)                         \
            acc[i2][j2] = MFMA16(aL[i2], bL[j2], acc[i2][j2]);                   \
    __builtin_amdgcn_s_setprio(0);                                               \
    if (DOVM) asm volatile("s_waitcnt " VM ::: "memory");                        \
    __builtin_amdgcn_s_barrier();                                                \
} while (0)

    for (int tt = 0; tt < 14; tt += 2) {
        O_KSTEP(0, tt + 1, 1, true, "vmcnt(6)", true);
        O_KSTEP(1, tt + 2, 0, true, "vmcnt(6)", true);
        O_KSTEP(2, tt + 2, 1, true, "vmcnt(6)", true);
        O_KSTEP(3, tt + 3, 0, true, "vmcnt(6)", true);
    }
    O_KSTEP(0, 15, 1, true,  "vmcnt(6)", true);   // p=28
    O_KSTEP(1, 0, 0, false, "vmcnt(3)", true);    // p=29
    O_KSTEP(2, 0, 0, false, "vmcnt(0)", true);    // p=30
    O_KSTEP(3, 0, 0, false, "vmcnt(0)", false);   // p=31
#undef O_KSTEP

#pragma unroll
    for (int mf = 0; mf < 4; ++mf) {
        const int mbase = m0 + wm * 64 + mf * 16 + quad * 4;
#pragma unroll
        for (int nf = 0; nf < 4; ++nf) {
            const int n = n0 + wn * 64 + nf * 16 + l16;
#pragma unroll
            for (int r = 0; r < 4; ++r)
                C[(size_t)(mbase + r) * Dn + n] = acc[mf][nf][r];
        }
    }
}

// ---------------- flash v5 (R6/R9 version, single-buffer) ----------------
// R7's K/V double-buffer REGRESSED (-6us): 48KB LDS cut occupancy 5->3
// blocks/CU while K/V (512KB/head) is L2-resident across the 16 q-tile
// blocks per bh -> staging latency was already TLP-hidden (Common-mistake
// #7). Blocks sharing bh are 64 apart -> same XCD (64 % 8 == 0).
__global__ __launch_bounds__(256) void flashv5(const _Float16* __restrict__ Q,
                                               const _Float16* __restrict__ K,
                                               const _Float16* __restrict__ Vt,
                                               _Float16* __restrict__ O)
{
    __shared__ __align__(16) _Float16 KS[64 * 64];     // [key][dk], chunk-swizzled
    __shared__ __align__(16) _Float16 VS[64 * 64];     // [dk][key], chunk-swizzled
    __shared__ __align__(16) _Float16 Ps[4][32 * 64];  // per-wave P, chunk-swizzled

    const int t = threadIdx.x;
    const int lane = t & 63, w = t >> 6;
    const int quad = lane >> 4, l16 = lane & 15;
    const int bh = blockIdx.x & 63;                    // fast-varying (L2 locality)
    const int qtile = 15 - (blockIdx.x >> 6);          // heaviest first
    const int b = bh >> 4, h = bh & 15;
    const int qb = qtile * 128 + w * 32;

    const _Float16* Qg = Q  + (size_t)bh * Nn * DKn;
    const _Float16* Kg = K  + (size_t)bh * Nn * DKn;
    const _Float16* Vg = Vt + (size_t)bh * DKn * Nn;

    auto stage = [&](int kt) {
        const int k0 = kt * 64;
#pragma unroll
        for (int jj = 0; jj < 2; ++jj) {
            const int ci = jj * 256 + w * 64 + lane;   // slot (r*8 + c)
            const int r = ci >> 3, c = ci & 7;
            const int gc = (c ^ (r & 7)) * 8;          // XOR chunk swizzle
            load_lds16(Kg + (size_t)(k0 + r) * DKn + gc, &KS[(jj * 256 + w * 64) * 8]);
            load_lds16(Vg + (size_t)r * Nn + k0 + gc,    &VS[(jj * 256 + w * 64) * 8]);
        }
    };
#define SWZ(arr, r, c) (*(const v8h*)&(arr)[(r) * 64 + (((c) ^ ((r) & 7)) * 8)])

    v8h qf[2][2];
#pragma unroll
    for (int qq = 0; qq < 2; ++qq)
#pragma unroll
        for (int ks = 0; ks < 2; ++ks)
            qf[qq][ks] = *(const v8h*)&Qg[(size_t)(qb + qq * 16 + l16) * DKn + ks * 32 + quad * 8];

    v8h ones;
#pragma unroll
    for (int i = 0; i < 8; ++i) ones[i] = (_Float16)1.0f;

    v4f o[2][4];
#pragma unroll
    for (int mq = 0; mq < 2; ++mq)
#pragma unroll
        for (int nt = 0; nt < 4; ++nt) o[mq][nt] = v4f{0.f, 0.f, 0.f, 0.f};
    v4f ol[2] = {v4f{0.f, 0.f, 0.f, 0.f}, v4f{0.f, 0.f, 0.f, 0.f}};

    const int NKT  = 2 * qtile + 2;                    // block-uniform
    const int diag = 2 * qtile + (w >> 1);             // wave's masked tile

    for (int kt = 0; kt < NKT; ++kt) {
        stage(kt);
        __syncthreads();                               // drains vmcnt (staging done)
        if (kt <= diag) {
            const int k0 = kt * 64;
            auto ptile = [&](bool domask) {
#pragma unroll
                for (int kk = 0; kk < 4; ++kk) {
                    v4f s0 = v4f{0.f, 0.f, 0.f, 0.f}, s1 = v4f{0.f, 0.f, 0.f, 0.f};
#pragma unroll
                    for (int ks = 0; ks < 2; ++ks) {
                        const v8h ak = SWZ(KS, kk * 16 + l16, ks * 4 + quad);
                        s0 = __builtin_amdgcn_mfma_f32_16x16x32_f16(ak, qf[0][ks], s0, 0, 0, 0);
                        s1 = __builtin_amdgcn_mfma_f32_16x16x32_f16(ak, qf[1][ks], s1, 0, 0, 0);
                    }
                    const int key0 = k0 + kk * 16 + quad * 4;
#pragma unroll
                    for (int qq = 0; qq < 2; ++qq) {
                        const v4f sv = qq ? s1 : s0;
                        const int q = qb + qq * 16 + l16;
                        float p[4];
#pragma unroll
                        for (int r = 0; r < 4; ++r) {
                            float x = sv[r];
                            if (domask) x = (key0 + r > q) ? -1e9f : x;
                            p[r] = FEXP2(x);           // Q pre-scaled by log2e/8
                        }
                        f2x2 pkr;
                        pkr.lo = __builtin_amdgcn_cvt_pkrtz(p[0], p[1]);
                        pkr.hi = __builtin_amdgcn_cvt_pkrtz(p[2], p[3]);
                        const h4 pk = __builtin_bit_cast(h4, pkr);
                        const int prow = qq * 16 + l16;
                        const int pch  = kk * 2 + (quad >> 1);
                        *(h4*)&Ps[w][prow * 64 + ((pch ^ (prow & 7)) * 8 + (quad & 1) * 4)] = pk;
                    }
                }
#pragma unroll
                for (int ks = 0; ks < 2; ++ks)
#pragma unroll
                    for (int mq = 0; mq < 2; ++mq) {
                        const int arow = mq * 16 + l16;
                        const int ach  = ks * 4 + quad;
                        const v8h a = *(const v8h*)&Ps[w][arow * 64 + ((ach ^ (arow & 7)) * 8)];
#pragma unroll
                        for (int nt = 0; nt < 4; ++nt) {
                            const v8h bvv = SWZ(VS, nt * 16 + l16, ks * 4 + quad);
                            o[mq][nt] = __builtin_amdgcn_mfma_f32_16x16x32_f16(a, bvv, o[mq][nt], 0, 0, 0);
                        }
                        ol[mq] = __builtin_amdgcn_mfma_f32_16x16x32_f16(a, ones, ol[mq], 0, 0, 0);
                    }
            };
            if (kt == diag) ptile(true); else ptile(false);
        }
        __syncthreads();                               // all reads done before next stage
    }
#undef SWZ

    _Float16* Op = O + (size_t)b * Nn * Dn + h * DKn;
#pragma unroll
    for (int mq = 0; mq < 2; ++mq)
#pragma unroll
        for (int r = 0; r < 4; ++r) {
            const float li = 1.0f / ol[mq][r];
            const int qrow = qb + mq * 16 + quad * 4 + r;
#pragma unroll
            for (int nt = 0; nt < 4; ++nt)
                Op[(size_t)qrow * Dn + nt * 16 + l16] = (_Float16)(o[mq][nt][r] * li);
        }
}

extern "C" void kernel_launch(void* const* d_in, const int* in_sizes, int n_in,
                              void* d_out, int out_size, void* d_ws, size_t ws_size,
                              hipStream_t stream)
{
    const float* X  = (const float*)d_in[0];
    // d_in[1] = additive causal mask; regenerated inline in flashv5.
    const float* Wq = (const float*)d_in[2];
    const float* Wk = (const float*)d_in[3];
    const float* Wv = (const float*)d_in[4];
    const float* Wo = (const float*)d_in[5];

    char* ws = (char*)d_ws;
    _Float16* Xh   = (_Float16*)ws;                      // 16 MB
    _Float16* Wqkv = (_Float16*)(ws + (16u << 20));      // 6 MB  [3072][1024]
    _Float16* Wto  = Wqkv + (3u << 20);                  // 2 MB
    _Float16* Qh   = Wto + (1u << 20);                   // 16 MB each
    _Float16* Kh   = Qh + (size_t)Mn * Dn;
    _Float16* Vth  = Kh + (size_t)Mn * Dn;
    _Float16* Ah   = Vth + (size_t)Mn * Dn;              // total 88 MB

    castAll<<<12288, 256, 0, stream>>>(X, Xh, Wq, Wk, Wv, Wo, Wqkv, Wto);
    gemmqkv<<<512, 512, 0, stream>>>(Xh, Wqkv, Qh, Kh, Vth);
    flashv5<<<1024, 256, 0, stream>>>(Qh, Kh, Vth, Ah);
    gemmo<<<256, 512, 0, stream>>>(Ah, Wto, (float*)d_out);
}

// Round 12
// 245.970 us; speedup vs baseline: 1.0705x; 1.0151x over previous
//
#include <hip/hip_runtime.h>

typedef __fp16   f2  __attribute__((ext_vector_type(2)));
typedef _Float16 h4  __attribute__((ext_vector_type(4)));
typedef _Float16 v8h __attribute__((ext_vector_type(8)));
typedef float    v4f __attribute__((ext_vector_type(4)));
struct f2x2 { f2 lo, hi; };

#if __has_builtin(__builtin_amdgcn_exp2f)
#define FEXP2(x) __builtin_amdgcn_exp2f(x)   // raw v_exp_f32 (no ocml fixups)
#else
#define FEXP2(x) exp2f(x)
#endif

constexpr int Bn = 4, Nn = 2048, Dn = 1024, Hn = 16, DKn = 64, Mn = 8192;

// async global->LDS, 16B per lane; LDS dest = wave-uniform base + lane*16 (m104)
__device__ __forceinline__ void load_lds16(const _Float16* g, _Float16* l) {
    __builtin_amdgcn_global_load_lds(
        (const __attribute__((address_space(1))) void*)g,
        (__attribute__((address_space(3))) void*)l, 16, 0, 0);
}

// ---- merged cast kernel: blocks [0,8192) = X fp32->f16; [8192,12288) = W transpose+cast ----
__global__ __launch_bounds__(256) void castAll(const float* __restrict__ x,
                                               _Float16* __restrict__ y,
                                               const float* __restrict__ Wq,
                                               const float* __restrict__ Wk,
                                               const float* __restrict__ Wv,
                                               const float* __restrict__ Wo,
                                               _Float16* __restrict__ Wqkv,
                                               _Float16* __restrict__ Wto) {
    __shared__ float tile[32][33];
    const int t = threadIdx.x;
    if (blockIdx.x < 8192) {
        const int i = blockIdx.x * 256 + t;
        const float4 v = ((const float4*)x)[i];
        h4 o; o[0] = (_Float16)v.x; o[1] = (_Float16)v.y;
        o[2] = (_Float16)v.z; o[3] = (_Float16)v.w;
        ((h4*)y)[i] = o;
        return;
    }
    const int wb = blockIdx.x - 8192;
    const int which = wb >> 10, bid = wb & 1023;
    const float* W = which == 0 ? Wq : which == 1 ? Wk : which == 2 ? Wv : Wo;
    _Float16* Dst = which < 3 ? (Wqkv + ((size_t)which << 20)) : Wto;
    const int bx = bid & 31, by = bid >> 5;
    const int r = t >> 3, c4 = (t & 7) * 4;
    const float4 v = *(const float4*)&W[(size_t)(by * 32 + r) * Dn + bx * 32 + c4];
    tile[r][c4 + 0] = v.x; tile[r][c4 + 1] = v.y;
    tile[r][c4 + 2] = v.z; tile[r][c4 + 3] = v.w;
    __syncthreads();
    h4 o;
    o[0] = (_Float16)tile[c4 + 0][r];
    o[1] = (_Float16)tile[c4 + 1][r];
    o[2] = (_Float16)tile[c4 + 2][r];
    o[3] = (_Float16)tile[c4 + 3][r];
    *(h4*)&Dst[(size_t)(bx * 32 + r) * Dn + by * 32 + c4] = o;
}

// ======================================================================
// GEMMs: R11 config (best measured: gemmqkv 71.7us, 2689 cyc/K-step).
// QKV 256x192 tile, grid 512 = exactly 2 rounds; gemmo 256x128, grid 256 =
// 1 round. 4-region stage-3-ahead counted-vmcnt schedule (ledger R3/R6),
// R2 bank-conflict-free swizzle (0 conflicts), bijective XCD block map
// (FETCH 78.9 -> 57.4MB).
// ======================================================================
#define MFMA16(A, B, C) __builtin_amdgcn_mfma_f32_16x16x32_f16((A), (B), (C), 0, 0, 0)

// ---------- fused QKV GEMM: [8192,1024] @ [3072,1024]^T ----------
// 256x192 tile, per-wave 128x48 (2M x 4N). grid 32*16 = 512 blocks.
__global__ __launch_bounds__(512, 2) void gemmqkv(const _Float16* __restrict__ A,
                                                  const _Float16* __restrict__ Wt,
                                                  _Float16* __restrict__ Qo,
                                                  _Float16* __restrict__ Ko,
                                                  _Float16* __restrict__ Vo)
{
    __shared__ __align__(16) _Float16 As[4 * 8192];
    __shared__ __align__(16) _Float16 Bs[4 * 6144];
    // XCD swizzle: 512 % 8 == 0 -> bijective chunked map (64 tiles/XCD,
    // = 4 contiguous A-panels per XCD)
    const int wgid = (blockIdx.x & 7) * 64 + (blockIdx.x >> 3);
    const int bx = wgid & 15, by = wgid >> 4;
    const int m0 = by * 256, n0 = bx * 192;
    const _Float16* Abase = A + (size_t)m0 * Dn;
    const _Float16* Bbase = Wt + (size_t)n0 * Dn;

    const int t = threadIdx.x, lane = t & 63, w = t >> 6;
    const int quad = lane >> 4, l16 = lane & 15;
    const int wm = w >> 2, wn = w & 3;
    const int rA = t >> 2;
    const int gc = ((t & 3) ^ ((t >> 3) & 3)) * 8;   // source-side XOR swizzle
    const _Float16* pA0 = Abase + (size_t)rA * Dn + gc;
    const _Float16* pA1 = pA0 + (size_t)128 * Dn;    // A rows 128..255
    const _Float16* pB0 = Bbase + (size_t)rA * Dn + gc;
    const _Float16* pB1 = pB0 + (size_t)128 * Dn;    // B rows 128..191 (t<256)
    auto stageA = [&](int ts, int sh) {
        const int reg = (ts & 1) * 2 + sh, ko = ts * 64 + sh * 32;
        load_lds16(pA0 + ko, As + reg * 8192 + w * 512);
        load_lds16(pA1 + ko, As + reg * 8192 + 4096 + w * 512);
    };
    auto stageB = [&](int ts, int sh) {
        const int reg = (ts & 1) * 2 + sh, ko = ts * 64 + sh * 32;
        load_lds16(pB0 + ko, Bs + reg * 6144 + w * 512);
        if (t < 256)                                  // rows 128..191 only
            load_lds16(pB1 + ko, Bs + reg * 6144 + 4096 + w * 512);
    };
    const int swz  = (quad ^ ((l16 >> 1) & 3)) * 8;
    const int aoff = (wm * 128 + l16) * 32 + swz;
    const int boff = (wn * 48 + l16) * 32 + swz;

    v4f acc[8][3];
#pragma unroll
    for (int i = 0; i < 8; ++i)
#pragma unroll
        for (int j = 0; j < 3; ++j) acc[i][j] = v4f{0.f, 0.f, 0.f, 0.f};

    // prologue: slots 0,1,2 (A,B pairs in order); vmcnt(6) -> slot 0 done
    stageA(0, 0); stageB(0, 0); stageA(0, 1); stageB(0, 1); stageA(1, 0); stageB(1, 0);
    asm volatile("s_waitcnt vmcnt(6)" ::: "memory");
    __builtin_amdgcn_s_barrier();

#define QKV_KSTEP(REG, TS, SH, DOST, VM, DOVM) do {                              \
    const _Float16* Ab_ = As + (REG) * 8192 + aoff;                              \
    const _Float16* Bb_ = Bs + (REG) * 6144 + boff;                              \
    v8h aL[4], aH[4], bL[3];                                                     \
    _Pragma("unroll") for (int q2 = 0; q2 < 4; ++q2)                             \
        aL[q2] = *(const v8h*)(Ab_ + q2 * 512);                                  \
    _Pragma("unroll") for (int q2 = 0; q2 < 3; ++q2)                             \
        bL[q2] = *(const v8h*)(Bb_ + q2 * 512);                                  \
    if (DOST) stageA((TS), (SH));                                                \
    __builtin_amdgcn_s_barrier();                                                \
    asm volatile("s_waitcnt lgkmcnt(0)" ::: "memory");                           \
    __builtin_amdgcn_s_setprio(1);                                               \
    _Pragma("unroll") for (int i2 = 0; i2 < 4; ++i2)                             \
        _Pragma("unroll") for (int j2 = 0; j2 < 3; ++j2)                         \
            acc[i2][j2] = MFMA16(aL[i2], bL[j2], acc[i2][j2]);                   \
    __builtin_amdgcn_s_setprio(0);                                               \
    __builtin_amdgcn_s_barrier();                                                \
    _Pragma("unroll") for (int q2 = 0; q2 < 4; ++q2)                             \
        aH[q2] = *(const v8h*)(Ab_ + 2048 + q2 * 512);                           \
    if (DOST) stageB((TS), (SH));                                                \
    __builtin_amdgcn_s_barrier();                                                \
    asm volatile("s_waitcnt lgkmcnt(0)" ::: "memory");                           \
    __builtin_amdgcn_s_setprio(1);                                               \
    _Pragma("unroll") for (int i2 = 0; i2 < 4; ++i2)                             \
        _Pragma("unroll") for (int j2 = 0; j2 < 3; ++j2)                         \
            acc[4 + i2][j2] = MFMA16(aH[i2], bL[j2], acc[4 + i2][j2]);           \
    __builtin_amdgcn_s_setprio(0);                                               \
    if (DOVM) asm volatile("s_waitcnt " VM ::: "memory");                        \
    __builtin_amdgcn_s_barrier();                                                \
} while (0)

    // 32 K-steps; main loop p=0..27, peel 28..31 with tapered waits
    for (int tt = 0; tt < 14; tt += 2) {
        QKV_KSTEP(0, tt + 1, 1, true, "vmcnt(6)", true);
        QKV_KSTEP(1, tt + 2, 0, true, "vmcnt(6)", true);
        QKV_KSTEP(2, tt + 2, 1, true, "vmcnt(6)", true);
        QKV_KSTEP(3, tt + 3, 0, true, "vmcnt(6)", true);
    }
    QKV_KSTEP(0, 15, 1, true,  "vmcnt(6)", true);   // p=28: stages last slot 31
    QKV_KSTEP(1, 0, 0, false, "vmcnt(3)", true);    // p=29
    QKV_KSTEP(2, 0, 0, false, "vmcnt(0)", true);    // p=30
    QKV_KSTEP(3, 0, 0, false, "vmcnt(0)", false);   // p=31 (no wait)
#undef QKV_KSTEP

    // Epilogue: section resolved per column group (192 spans Q/K/V bounds).
#pragma unroll
    for (int mf = 0; mf < 8; ++mf) {
        const int mbase = m0 + wm * 128 + mf * 16 + quad * 4;
        const int b = mbase >> 11, nr = mbase & (Nn - 1);  // +r never crosses
#pragma unroll
        for (int nf = 0; nf < 3; ++nf) {
            const int nG = n0 + wn * 48 + nf * 16 + l16;   // [0, 3072)
            const int sec = nG >> 10, nl = nG & 1023;
            const int h = nl >> 6, dk = nl & 63;
            if (sec < 2) {
                _Float16* C = sec ? Ko : Qo;
                // Q pre-scaled by 1/sqrt(DK) * log2(e) so flash uses exp2
                const float scale = sec ? 1.0f : 0.125f * 1.44269504f;
#pragma unroll
                for (int r = 0; r < 4; ++r)
                    C[((size_t)(b * Hn + h) * Nn + (nr + r)) * DKn + dk] =
                        (_Float16)(acc[mf][nf][r] * scale);
            } else {
                h4 o; o[0] = (_Float16)acc[mf][nf][0]; o[1] = (_Float16)acc[mf][nf][1];
                o[2] = (_Float16)acc[mf][nf][2]; o[3] = (_Float16)acc[mf][nf][3];
                *(h4*)&Vo[((size_t)(b * Hn + h) * DKn + dk) * Nn + nr] = o;
            }
        }
    }
}

// ---------- output GEMM: [8192,1024] @ [1024,1024]^T -> fp32 row-major ----------
// 256x128 tile (grid 256 = exactly 1 full round of 256 CUs), per-wave 64x64.
__global__ __launch_bounds__(512, 2) void gemmo(const _Float16* __restrict__ A,
                                                const _Float16* __restrict__ Wt,
                                                float* __restrict__ C)
{
    __shared__ __align__(16) _Float16 As[4 * 8192];
    __shared__ __align__(16) _Float16 Bs[4 * 4096];
    // XCD swizzle: 256 % 8 == 0 -> 32 tiles/XCD, contiguous (by,bx) range
    const int wgid = (blockIdx.x & 7) * 32 + (blockIdx.x >> 3);
    const int bx = wgid & 7, by = wgid >> 3;
    const int m0 = by * 256, n0 = bx * 128;
    const _Float16* Abase = A + (size_t)m0 * Dn;
    const _Float16* Bbase = Wt + (size_t)n0 * Dn;

    const int t = threadIdx.x, lane = t & 63, w = t >> 6;
    const int quad = lane >> 4, l16 = lane & 15;
    const int wm = w & 3, wn = w >> 2;
    const int rA = t >> 2;
    const int gc = ((t & 3) ^ ((t >> 3) & 3)) * 8;
    const _Float16* pA0 = Abase + (size_t)rA * Dn + gc;
    const _Float16* pA1 = pA0 + (size_t)128 * Dn;
    const _Float16* pB0 = Bbase + (size_t)rA * Dn + gc;
    auto stage3 = [&](int ts, int sh) {
        const int reg = (ts & 1) * 2 + sh, ko = ts * 64 + sh * 32;
        load_lds16(pA0 + ko, As + reg * 8192 + w * 512);
        load_lds16(pA1 + ko, As + reg * 8192 + 4096 + w * 512);
        load_lds16(pB0 + ko, Bs + reg * 4096 + w * 512);
    };
    const int swz  = (quad ^ ((l16 >> 1) & 3)) * 8;
    const int aoff = (wm * 64 + l16) * 32 + swz;
    const int boff = (wn * 64 + l16) * 32 + swz;

    v4f acc[4][4];
#pragma unroll
    for (int i = 0; i < 4; ++i)
#pragma unroll
        for (int j = 0; j < 4; ++j) acc[i][j] = v4f{0.f, 0.f, 0.f, 0.f};

    stage3(0, 0); stage3(0, 1); stage3(1, 0);    // prologue: slots 0,1,2
    asm volatile("s_waitcnt vmcnt(6)" ::: "memory");
    __builtin_amdgcn_s_barrier();

#define O_KSTEP(REG, TS, SH, DOST, VM, DOVM) do {                                \
    const _Float16* Ab_ = As + (REG) * 8192 + aoff;                              \
    const _Float16* Bb_ = Bs + (REG) * 4096 + boff;                              \
    v8h aL[4], bL[4];                                                            \
    _Pragma("unroll") for (int q2 = 0; q2 < 4; ++q2) {                           \
        aL[q2] = *(const v8h*)(Ab_ + q2 * 512);                                  \
        bL[q2] = *(const v8h*)(Bb_ + q2 * 512);                                  \
    }                                                                            \
    if (DOST) stage3((TS), (SH));                                                \
    __builtin_amdgcn_s_barrier();                                                \
    asm volatile("s_waitcnt lgkmcnt(0)" ::: "memory");                           \
    __builtin_amdgcn_s_setprio(1);                                               \
    _Pragma("unroll") for (int i2 = 0; i2 < 4; ++i2)                             \
        _Pragma("unroll") for (int j2 = 0; j2 < 4; ++j2)                         \
            acc[i2][j2] = MFMA16(aL[i2], bL[j2], acc[i2][j2]);                   \
    __builtin_amdgcn_s_setprio(0);                                               \
    if (DOVM) asm volatile("s_waitcnt " VM ::: "memory");                        \
    __builtin_amdgcn_s_barrier();                                                \
} while (0)

    for (int tt = 0; tt < 14; tt += 2) {
        O_KSTEP(0, tt + 1, 1, true, "vmcnt(6)", true);
        O_KSTEP(1, tt + 2, 0, true, "vmcnt(6)", true);
        O_KSTEP(2, tt + 2, 1, true, "vmcnt(6)", true);
        O_KSTEP(3, tt + 3, 0, true, "vmcnt(6)", true);
    }
    O_KSTEP(0, 15, 1, true,  "vmcnt(6)", true);   // p=28
    O_KSTEP(1, 0, 0, false, "vmcnt(3)", true);    // p=29
    O_KSTEP(2, 0, 0, false, "vmcnt(0)", true);    // p=30
    O_KSTEP(3, 0, 0, false, "vmcnt(0)", false);   // p=31
#undef O_KSTEP

#pragma unroll
    for (int mf = 0; mf < 4; ++mf) {
        const int mbase = m0 + wm * 64 + mf * 16 + quad * 4;
#pragma unroll
        for (int nf = 0; nf < 4; ++nf) {
            const int n = n0 + wn * 64 + nf * 16 + l16;
#pragma unroll
            for (int r = 0; r < 4; ++r)
                C[(size_t)(mbase + r) * Dn + n] = acc[mf][nf][r];
        }
    }
}

// ---------------- flash v6: complementary-qtile pairing ----------------
// R12 change: load balance. Old grid 1024 (1 qtile/block) gave per-CU tile
// totals {80,72,64,56} (qtile sets {15-k,11-k,7-k,3-k}) -> makespan tracks
// the 80-tile CUs, ~15% idle tail. New grid 512: block (p, bh) runs qtile
// 15-p THEN qtile p sequentially -> every block exactly (2(15-p)+2) +
// (2p+2) = 34 tiles; 2 blocks/CU -> 68 tiles/CU uniform.
// Pass-2 safety: the K-loop's trailing __syncthreads separates pass-1's
// last LDS reads from pass-2's first stage; epilogue is register/global
// only. Single-buffer 32KB K/V kept (R7: dbuf regressed, L2-resident).
__global__ __launch_bounds__(256) void flashv5(const _Float16* __restrict__ Q,
                                               const _Float16* __restrict__ K,
                                               const _Float16* __restrict__ Vt,
                                               _Float16* __restrict__ O)
{
    __shared__ __align__(16) _Float16 KS[64 * 64];     // [key][dk], chunk-swizzled
    __shared__ __align__(16) _Float16 VS[64 * 64];     // [dk][key], chunk-swizzled
    __shared__ __align__(16) _Float16 Ps[4][32 * 64];  // per-wave P, chunk-swizzled

    const int t = threadIdx.x;
    const int lane = t & 63, w = t >> 6;
    const int quad = lane >> 4, l16 = lane & 15;
    const int bh = blockIdx.x & 63;                    // fast-varying (L2 locality)
    const int pr = blockIdx.x >> 6;                    // 0..7: pair index
    const int b = bh >> 4, h = bh & 15;

    const _Float16* Qg = Q  + (size_t)bh * Nn * DKn;
    const _Float16* Kg = K  + (size_t)bh * Nn * DKn;
    const _Float16* Vg = Vt + (size_t)bh * DKn * Nn;

    auto stage = [&](int kt) {
        const int k0 = kt * 64;
#pragma unroll
        for (int jj = 0; jj < 2; ++jj) {
            const int ci = jj * 256 + w * 64 + lane;   // slot (r*8 + c)
            const int r = ci >> 3, c = ci & 7;
            const int gc = (c ^ (r & 7)) * 8;          // XOR chunk swizzle
            load_lds16(Kg + (size_t)(k0 + r) * DKn + gc, &KS[(jj * 256 + w * 64) * 8]);
            load_lds16(Vg + (size_t)r * Nn + k0 + gc,    &VS[(jj * 256 + w * 64) * 8]);
        }
    };
#define SWZ(arr, r, c) (*(const v8h*)&(arr)[(r) * 64 + (((c) ^ ((r) & 7)) * 8)])

    v8h ones;
#pragma unroll
    for (int i = 0; i < 8; ++i) ones[i] = (_Float16)1.0f;

    _Float16* Op = O + (size_t)b * Nn * Dn + h * DKn;

    for (int pass = 0; pass < 2; ++pass) {
        const int qtile = pass ? pr : 15 - pr;
        const int qb = qtile * 128 + w * 32;

        v8h qf[2][2];
#pragma unroll
        for (int qq = 0; qq < 2; ++qq)
#pragma unroll
            for (int ks = 0; ks < 2; ++ks)
                qf[qq][ks] = *(const v8h*)&Qg[(size_t)(qb + qq * 16 + l16) * DKn + ks * 32 + quad * 8];

        v4f o[2][4];
#pragma unroll
        for (int mq = 0; mq < 2; ++mq)
#pragma unroll
            for (int nt = 0; nt < 4; ++nt) o[mq][nt] = v4f{0.f, 0.f, 0.f, 0.f};
        v4f ol[2] = {v4f{0.f, 0.f, 0.f, 0.f}, v4f{0.f, 0.f, 0.f, 0.f}};

        const int NKT  = 2 * qtile + 2;                // block-uniform
        const int diag = 2 * qtile + (w >> 1);         // wave's masked tile

        for (int kt = 0; kt < NKT; ++kt) {
            stage(kt);
            __syncthreads();                           // drains vmcnt (staging done)
            if (kt <= diag) {
                const int k0 = kt * 64;
                auto ptile = [&](bool domask) {
#pragma unroll
                    for (int kk = 0; kk < 4; ++kk) {
                        v4f s0 = v4f{0.f, 0.f, 0.f, 0.f}, s1 = v4f{0.f, 0.f, 0.f, 0.f};
#pragma unroll
                        for (int ks = 0; ks < 2; ++ks) {
                            const v8h ak = SWZ(KS, kk * 16 + l16, ks * 4 + quad);
                            s0 = __builtin_amdgcn_mfma_f32_16x16x32_f16(ak, qf[0][ks], s0, 0, 0, 0);
                            s1 = __builtin_amdgcn_mfma_f32_16x16x32_f16(ak, qf[1][ks], s1, 0, 0, 0);
                        }
                        const int key0 = k0 + kk * 16 + quad * 4;
#pragma unroll
                        for (int qq = 0; qq < 2; ++qq) {
                            const v4f sv = qq ? s1 : s0;
                            const int q = qb + qq * 16 + l16;
                            float p[4];
#pragma unroll
                            for (int r = 0; r < 4; ++r) {
                                float x = sv[r];
                                if (domask) x = (key0 + r > q) ? -1e9f : x;
                                p[r] = FEXP2(x);       // Q pre-scaled by log2e/8
                            }
                            f2x2 pkr;
                            pkr.lo = __builtin_amdgcn_cvt_pkrtz(p[0], p[1]);
                            pkr.hi = __builtin_amdgcn_cvt_pkrtz(p[2], p[3]);
                            const h4 pk = __builtin_bit_cast(h4, pkr);
                            const int prow = qq * 16 + l16;
                            const int pch  = kk * 2 + (quad >> 1);
                            *(h4*)&Ps[w][prow * 64 + ((pch ^ (prow & 7)) * 8 + (quad & 1) * 4)] = pk;
                        }
                    }
#pragma unroll
                    for (int ks = 0; ks < 2; ++ks)
#pragma unroll
                        for (int mq = 0; mq < 2; ++mq) {
                            const int arow = mq * 16 + l16;
                            const int ach  = ks * 4 + quad;
                            const v8h a = *(const v8h*)&Ps[w][arow * 64 + ((ach ^ (arow & 7)) * 8)];
#pragma unroll
                            for (int nt = 0; nt < 4; ++nt) {
                                const v8h bvv = SWZ(VS, nt * 16 + l16, ks * 4 + quad);
                                o[mq][nt] = __builtin_amdgcn_mfma_f32_16x16x32_f16(a, bvv, o[mq][nt], 0, 0, 0);
                            }
                            ol[mq] = __builtin_amdgcn_mfma_f32_16x16x32_f16(a, ones, ol[mq], 0, 0, 0);
                        }
                };
                if (kt == diag) ptile(true); else ptile(false);
            }
            __syncthreads();                           // all reads done before next stage
        }

#pragma unroll
        for (int mq = 0; mq < 2; ++mq)
#pragma unroll
            for (int r = 0; r < 4; ++r) {
                const float li = 1.0f / ol[mq][r];
                const int qrow = qb + mq * 16 + quad * 4 + r;
#pragma unroll
                for (int nt = 0; nt < 4; ++nt)
                    Op[(size_t)qrow * Dn + nt * 16 + l16] = (_Float16)(o[mq][nt][r] * li);
            }
    }
#undef SWZ
}

extern "C" void kernel_launch(void* const* d_in, const int* in_sizes, int n_in,
                              void* d_out, int out_size, void* d_ws, size_t ws_size,
                              hipStream_t stream)
{
    const float* X  = (const float*)d_in[0];
    // d_in[1] = additive causal mask; regenerated inline in flashv5.
    const float* Wq = (const float*)d_in[2];
    const float* Wk = (const float*)d_in[3];
    const float* Wv = (const float*)d_in[4];
    const float* Wo = (const float*)d_in[5];

    char* ws = (char*)d_ws;
    _Float16* Xh   = (_Float16*)ws;                      // 16 MB
    _Float16* Wqkv = (_Float16*)(ws + (16u << 20));      // 6 MB  [3072][1024]
    _Float16* Wto  = Wqkv + (3u << 20);                  // 2 MB
    _Float16* Qh   = Wto + (1u << 20);                   // 16 MB each
    _Float16* Kh   = Qh + (size_t)Mn * Dn;
    _Float16* Vth  = Kh + (size_t)Mn * Dn;
    _Float16* Ah   = Vth + (size_t)Mn * Dn;              // total 88 MB

    castAll<<<12288, 256, 0, stream>>>(X, Xh, Wq, Wk, Wv, Wo, Wqkv, Wto);
    gemmqkv<<<512, 512, 0, stream>>>(Xh, Wqkv, Qh, Kh, Vth);
    flashv5<<<512, 256, 0, stream>>>(Qh, Kh, Vth, Ah);
    gemmo<<<256, 512, 0, stream>>>(Ah, Wto, (float*)d_out);
}